// Round 9
// baseline (198.946 us; speedup 1.0000x reference)
//
#include <hip/hip_runtime.h>

#define R 256
#define T 32

#define TROWS 16        // out tile rows
#define TCOLS 32        // out tile cols
#define XROWS 20        // x tile rows (halo 2)
#define XCOLS 36        // x tile cols (halo 2)
#define HR 18           // hidden rows stored (out rows + halo 1)
#define HC 34           // hidden cols stored (out cols + halo 1)
#define HSTR 36         // hidden row stride (words); hs col = hidden col + 1
#define CP 648          // plane stride words = 18*36; %32=8 -> cl bank offsets {0,8,16,24}; %4==0
#define NPX (HR * HC)   // 612 hidden px per tile

// ---------------------------------------------------------------------------
// Kernel A (unchanged R8 — dedup'd staging, known-good)
// ---------------------------------------------------------------------------
__global__ __launch_bounds__(256) void einsum_kernel(
    const float* __restrict__ yt, const float* __restrict__ Ht,
    float* __restrict__ x) {
  const int idx = blockIdx.x;
  const int rh  = idx >> 8;
  const int yy  = (idx & 255) >> 2;
  const int bq  = idx & 3;
  const int b0  = bq * 8;
  const int tid = threadIdx.x;
  const int q   = tid;
  const int q4  = q >> 2;

  __shared__ float yts[8 * 32 * 64];

#pragma unroll
  for (int i = 0; i < 16; ++i) {
    int f4  = tid + i * 256;
    int b_l = f4 >> 9;
    int t   = (f4 >> 4) & 31;
    int xx4 = f4 & 15;
    float4 v = *(const float4*)(yt + (((size_t)(b0 + b_l) * T + t) * 64 + yy) * 64 + xx4 * 4);
    *(float4*)(yts + f4 * 4) = v;
  }
  __syncthreads();

  for (int rr = 0; rr < 2; ++rr) {
    const int p = yy * 4 + rh * 2 + rr;
    float ht[T];
#pragma unroll
    for (int t = 0; t < T; ++t) ht[t] = Ht[((size_t)t * R + p) * R + q];

#pragma unroll
    for (int b_l = 0; b_l < 8; ++b_l) {
      const float* ys = yts + b_l * 2048 + q4;
      float acc = 0.f;
#pragma unroll
      for (int t = 0; t < T; ++t) acc += ht[t] * ys[t * 64];
      x[((size_t)(b0 + b_l) * R + p) * R + q] = acc;
    }
  }
}

// ---------------------------------------------------------------------------
// Kernel B: fused Conv(1->32,3x3) -> ReLU -> Conv(32->1,3x3), SAME.
// Software-pipelined: conv1(cg+1) -> buffer B while conv2(cg) reads buffer A;
// ONE barrier per channel group (9 total vs 16). Static dual __shared__
// buffers (unroll x2) keep every LDS offset an immediate.
// ---------------------------------------------------------------------------
template <bool EDGE>
__device__ __forceinline__ void conv1_group(
    int cg, const float (&patch)[5][9], bool slot4, const bool (&oob)[5],
    const int (&sw)[5], float* hsbuf,
    const float* __restrict__ W1, const float* __restrict__ b1) {
#pragma unroll
  for (int c = 0; c < 4; ++c) {
    const int ch = cg * 4 + c;            // wave-uniform -> SGPR weights
    const float bias = b1[ch];
#pragma unroll
    for (int it = 0; it < 5; ++it) {
      if (it < 4 || slot4) {
        float h = bias;
#pragma unroll
        for (int k = 0; k < 9; ++k) h += W1[ch * 9 + k] * patch[it][k];
        h = fmaxf(h, 0.f);
        if (EDGE) {
          if (oob[it]) h = 0.f;           // conv2 SAME: outside image = 0
        }
        hsbuf[c * CP + sw[it]] = h;
      }
    }
  }
}

__device__ __forceinline__ void conv2_group(
    int cg, const float* hsbuf, int hboff, const float* __restrict__ W2,
    int cl, float (&acc)[4][4]) {
  float w2[9];
#pragma unroll
  for (int k = 0; k < 9; ++k) w2[k] = W2[(cg * 4 + cl) * 9 + k];
#pragma unroll
  for (int j = 0; j < 6; ++j) {
    float4 v4 = *(const float4*)(hsbuf + hboff + j * HSTR);
    float2 v2 = *(const float2*)(hsbuf + hboff + j * HSTR + 4);
    float v[6] = {v4.x, v4.y, v4.z, v4.w, v2.x, v2.y};
#pragma unroll
    for (int dy = 0; dy < 3; ++dy) {
      int ai = j - dy;
      if (ai >= 0 && ai < 4) {
#pragma unroll
        for (int dx = 0; dx < 3; ++dx) {
          const float w = w2[dy * 3 + dx];
#pragma unroll
          for (int px = 0; px < 4; ++px) acc[ai][px] += w * v[px + dx];
        }
      }
    }
  }
}

__global__ __launch_bounds__(128) void conv_fused_kernel(
    const float* __restrict__ x, const float* __restrict__ W1,
    const float* __restrict__ b1, const float* __restrict__ W2,
    const float* __restrict__ b2, float* __restrict__ out) {
  __shared__ float xs[XROWS * XCOLS];  // 2880 B
  __shared__ float hsA[4 * CP];        // 10368 B
  __shared__ float hsB[4 * CP];        // 10368 B

  const int tid  = threadIdx.x;
  const int b    = blockIdx.x >> 7;
  const int tile = blockIdx.x & 127;
  const int oy0  = (tile >> 3) * TROWS;
  const int ox0  = (tile & 7) * TCOLS;
  const float* xb = x + (size_t)b * R * R;

  for (int i = tid; i < XROWS * XCOLS; i += 128) {
    int rr = i / XCOLS, cc = i % XCOLS;
    int gy = oy0 - 2 + rr, gx = ox0 - 2 + cc;
    float v = 0.f;
    if (gy >= 0 && gy < R && gx >= 0 && gx < R) v = xb[gy * R + gx];
    xs[i] = v;
  }
  __syncthreads();

  float patch[5][9];
  int  sw[5];
  bool oob[5];
  const bool slot4 = (tid < NPX - 4 * 128);
#pragma unroll
  for (int it = 0; it < 5; ++it) {
    int px = tid + it * 128;
    bool act = (it < 4) || slot4;
    int hy = act ? (px / HC) : 0;
    int hx = act ? (px % HC) : 0;
    sw[it] = hy * HSTR + hx;
    int ghy = oy0 - 1 + hy, ghx = ox0 - 1 + hx;
    oob[it] = !((ghy >= 0) & (ghy < R) & (ghx >= 0) & (ghx < R));
#pragma unroll
    for (int ky = 0; ky < 3; ++ky)
#pragma unroll
      for (int kx = 0; kx < 3; ++kx)
        patch[it][ky * 3 + kx] = act ? xs[(hy + ky) * XCOLS + hx + kx] : 0.f;
  }

  const int g  = tid & 7;
  const int cl = (tid >> 3) & 3;
  const int rh = tid >> 5;
  const int r0 = 4 * rh;

  float acc[4][4];
#pragma unroll
  for (int ai = 0; ai < 4; ++ai)
#pragma unroll
    for (int px = 0; px < 4; ++px) acc[ai][px] = 0.f;

  const int hboff = cl * CP + r0 * HSTR + 4 * g;

  const bool edge = (oy0 == 0) | (oy0 == R - TROWS) | (ox0 == 0) | (ox0 == R - TCOLS);

  if (edge) {
    conv1_group<true>(0, patch, slot4, oob, sw, hsA, W1, b1);
    __syncthreads();
#pragma unroll
    for (int i = 0; i < 4; ++i) {
      const int cg = 2 * i;
      if (cg + 1 < 8) conv1_group<true>(cg + 1, patch, slot4, oob, sw, hsB, W1, b1);
      conv2_group(cg, hsA, hboff, W2, cl, acc);
      __syncthreads();
      if (cg + 2 < 8) conv1_group<true>(cg + 2, patch, slot4, oob, sw, hsA, W1, b1);
      conv2_group(cg + 1, hsB, hboff, W2, cl, acc);
      __syncthreads();
    }
  } else {
    conv1_group<false>(0, patch, slot4, oob, sw, hsA, W1, b1);
    __syncthreads();
#pragma unroll
    for (int i = 0; i < 4; ++i) {
      const int cg = 2 * i;
      if (cg + 1 < 8) conv1_group<false>(cg + 1, patch, slot4, oob, sw, hsB, W1, b1);
      conv2_group(cg, hsA, hboff, W2, cl, acc);
      __syncthreads();
      if (cg + 2 < 8) conv1_group<false>(cg + 2, patch, slot4, oob, sw, hsA, W1, b1);
      conv2_group(cg + 1, hsB, hboff, W2, cl, acc);
      __syncthreads();
    }
  }

  const float bias2 = b2[0];
#pragma unroll
  for (int ai = 0; ai < 4; ++ai)
#pragma unroll
    for (int px = 0; px < 4; ++px) {
      float v = acc[ai][px];
      v += __shfl_xor(v, 8);
      v += __shfl_xor(v, 16);
      acc[ai][px] = v;
    }
  if (cl == 0) {
#pragma unroll
    for (int ai = 0; ai < 4; ++ai) {
      float4 o = {acc[ai][0] + bias2, acc[ai][1] + bias2,
                  acc[ai][2] + bias2, acc[ai][3] + bias2};
      *(float4*)(out + (size_t)b * R * R + (oy0 + r0 + ai) * R + ox0 + 4 * g) = o;
    }
  }
}

// ---------------------------------------------------------------------------
extern "C" void kernel_launch(void* const* d_in, const int* in_sizes, int n_in,
                              void* d_out, int out_size, void* d_ws, size_t ws_size,
                              hipStream_t stream) {
  const float* yt = (const float*)d_in[0];  // (32,32,64,64)
  const float* Ht = (const float*)d_in[1];  // (32,256,256)
  const float* W1 = (const float*)d_in[2];  // (32,1,3,3)
  const float* b1 = (const float*)d_in[3];  // (32,)
  const float* W2 = (const float*)d_in[4];  // (1,32,3,3)
  const float* b2 = (const float*)d_in[5];  // (1,)
  float* outp = (float*)d_out;              // (32,1,256,256)
  float* x    = (float*)d_ws;               // 8 MB scratch

  einsum_kernel<<<512, 256, 0, stream>>>(yt, Ht, x);
  conv_fused_kernel<<<4096, 128, 0, stream>>>(x, W1, b1, W2, b2, outp);
}

// Round 10
// 145.857 us; speedup vs baseline: 1.3640x; 1.3640x over previous
//
#include <hip/hip_runtime.h>

#define R 256
#define T 32

#define TROWS 8         // out tile rows (per wave)
#define TCOLS 32        // out tile cols
#define XROWS 12        // x tile rows (halo 2)
#define XCOLS 36        // x tile cols (halo 2)
#define HR 10           // hidden rows stored (out rows + halo 1)
#define HC 34           // hidden cols stored (out cols + halo 1)
#define HSTR 36         // hidden row stride (words); hs col = hidden col + 1
#define CP 360          // plane stride words = 10*36; %32=8 -> cl bank offsets {0,8,16,24}
#define NPX (HR * HC)   // 340 hidden px per tile
#define NSLOT 6         // ceil(340/64)

// ---------------------------------------------------------------------------
// Kernel A (unchanged R8 — dedup'd staging, known-good)
// ---------------------------------------------------------------------------
__global__ __launch_bounds__(256) void einsum_kernel(
    const float* __restrict__ yt, const float* __restrict__ Ht,
    float* __restrict__ x) {
  const int idx = blockIdx.x;
  const int rh  = idx >> 8;
  const int yy  = (idx & 255) >> 2;
  const int bq  = idx & 3;
  const int b0  = bq * 8;
  const int tid = threadIdx.x;
  const int q   = tid;
  const int q4  = q >> 2;

  __shared__ float yts[8 * 32 * 64];

#pragma unroll
  for (int i = 0; i < 16; ++i) {
    int f4  = tid + i * 256;
    int b_l = f4 >> 9;
    int t   = (f4 >> 4) & 31;
    int xx4 = f4 & 15;
    float4 v = *(const float4*)(yt + (((size_t)(b0 + b_l) * T + t) * 64 + yy) * 64 + xx4 * 4);
    *(float4*)(yts + f4 * 4) = v;
  }
  __syncthreads();

  for (int rr = 0; rr < 2; ++rr) {
    const int p = yy * 4 + rh * 2 + rr;
    float ht[T];
#pragma unroll
    for (int t = 0; t < T; ++t) ht[t] = Ht[((size_t)t * R + p) * R + q];

#pragma unroll
    for (int b_l = 0; b_l < 8; ++b_l) {
      const float* ys = yts + b_l * 2048 + q4;
      float acc = 0.f;
#pragma unroll
      for (int t = 0; t < T; ++t) acc += ht[t] * ys[t * 64];
      x[((size_t)(b0 + b_l) * R + p) * R + q] = acc;
    }
  }
}

// ---------------------------------------------------------------------------
// Kernel B: fused Conv(1->32,3x3) -> ReLU -> Conv(32->1,3x3), SAME.
// WAVE-PRIVATE tiles: 64-thread blocks, each wave owns a 32x8 output tile.
// conv1 writes and conv2 reads of hs are same-wave, so __syncthreads() in a
// single-wave workgroup is just a waitcnt fence (s_barrier elided) — no
// cross-wave rendezvous, stalls hidden by co-resident waves.
// ---------------------------------------------------------------------------
template <bool EDGE>
__device__ __forceinline__ void conv_body(
    const float (&patch)[NSLOT][9], bool slot5, const bool (&oob)[NSLOT],
    const int (&sw)[NSLOT], float* hs,
    const float* __restrict__ W1, const float* __restrict__ b1,
    const float* __restrict__ W2, int cl, int hboff, float (&acc)[4][4]) {
  for (int cg = 0; cg < 8; ++cg) {
    float w2[9];
#pragma unroll
    for (int k = 0; k < 9; ++k) w2[k] = W2[(cg * 4 + cl) * 9 + k];

    // ---- conv1 + relu: channels cg*4..cg*4+3 into planes 0..3 ----
#pragma unroll
    for (int c = 0; c < 4; ++c) {
      const int ch = cg * 4 + c;            // wave-uniform -> SGPR weights
      const float bias = b1[ch];
#pragma unroll
      for (int it = 0; it < NSLOT; ++it) {
        if (it < 5 || slot5) {              // slots 0..4 statically full
          float h = bias;
#pragma unroll
          for (int k = 0; k < 9; ++k) h += W1[ch * 9 + k] * patch[it][k];
          h = fmaxf(h, 0.f);
          if (EDGE) {
            if (oob[it]) h = 0.f;           // conv2 SAME: outside image = 0
          }
          hs[c * CP + sw[it]] = h;
        }
      }
    }
    __syncthreads();   // single-wave workgroup: waitcnt fence only

    // ---- conv2 partials: 6 rolling rows, each read once ----
#pragma unroll
    for (int j = 0; j < 6; ++j) {
      float4 v4 = *(const float4*)(hs + hboff + j * HSTR);
      float2 v2 = *(const float2*)(hs + hboff + j * HSTR + 4);
      float v[6] = {v4.x, v4.y, v4.z, v4.w, v2.x, v2.y};
#pragma unroll
      for (int dy = 0; dy < 3; ++dy) {
        int ai = j - dy;
        if (ai >= 0 && ai < 4) {
#pragma unroll
          for (int dx = 0; dx < 3; ++dx) {
            const float w = w2[dy * 3 + dx];
#pragma unroll
            for (int px = 0; px < 4; ++px) acc[ai][px] += w * v[px + dx];
          }
        }
      }
    }
    __syncthreads();   // WAR fence before next group's conv1 overwrites hs
  }
}

__global__ __launch_bounds__(64) void conv_fused_kernel(
    const float* __restrict__ x, const float* __restrict__ W1,
    const float* __restrict__ b1, const float* __restrict__ W2,
    const float* __restrict__ b2, float* __restrict__ out) {
  __shared__ float xs[XROWS * XCOLS];  // 1728 B
  __shared__ float hs[4 * CP];         // 5760 B

  const int tid  = threadIdx.x;        // lane
  const int b    = blockIdx.x >> 8;
  const int tile = blockIdx.x & 255;   // 32 row-tiles x 8 col-tiles
  const int oy0  = (tile >> 3) * TROWS;   // 0..248
  const int ox0  = (tile & 7) * TCOLS;    // 0..224
  const float* xb = x + (size_t)b * R * R;

  // --- stage x tile with halo 2, zero-padded ---
  for (int i = tid; i < XROWS * XCOLS; i += 64) {
    int rr = i / XCOLS, cc = i % XCOLS;
    int gy = oy0 - 2 + rr, gx = ox0 - 2 + cc;
    float v = 0.f;
    if (gy >= 0 && gy < R && gx >= 0 && gx < R) v = xb[gy * R + gx];
    xs[i] = v;
  }
  __syncthreads();

  // --- per-lane 3x3 patches for its hidden slots (10x34 grid, 340 px) ---
  float patch[NSLOT][9];
  int  sw[NSLOT];
  bool oob[NSLOT];
  const bool slot5 = (tid < NPX - 5 * 64);   // 20 lanes
#pragma unroll
  for (int it = 0; it < NSLOT; ++it) {
    int px = tid + it * 64;
    bool act = (it < 5) || slot5;
    int hy = act ? (px / HC) : 0;
    int hx = act ? (px % HC) : 0;
    sw[it] = hy * HSTR + hx;
    int ghy = oy0 - 1 + hy, ghx = ox0 - 1 + hx;
    oob[it] = !((ghy >= 0) & (ghy < R) & (ghx >= 0) & (ghx < R));
#pragma unroll
    for (int ky = 0; ky < 3; ++ky)
#pragma unroll
      for (int kx = 0; kx < 3; ++kx)
        patch[it][ky * 3 + kx] = act ? xs[(hy + ky) * XCOLS + hx + kx] : 0.f;
  }

  const int g  = tid & 7;          // col granule: px 4g..4g+3
  const int cl = (tid >> 3) & 3;   // channel in group
  const int rh = tid >> 5;         // 0..1: out rows 4rh..4rh+3
  const int r0 = 4 * rh;

  float acc[4][4];
#pragma unroll
  for (int ai = 0; ai < 4; ++ai)
#pragma unroll
    for (int px = 0; px < 4; ++px) acc[ai][px] = 0.f;

  const int hboff = cl * CP + r0 * HSTR + 4 * g;

  const bool edge = (oy0 == 0) | (oy0 == R - TROWS) | (ox0 == 0) | (ox0 == R - TCOLS);
  if (edge)
    conv_body<true>(patch, slot5, oob, sw, hs, W1, b1, W2, cl, hboff, acc);
  else
    conv_body<false>(patch, slot5, oob, sw, hs, W1, b1, W2, cl, hboff, acc);

  // ---- reduce over the 4 channels (lane xor 8,16) and store ----
  const float bias2 = b2[0];
#pragma unroll
  for (int ai = 0; ai < 4; ++ai)
#pragma unroll
    for (int px = 0; px < 4; ++px) {
      float v = acc[ai][px];
      v += __shfl_xor(v, 8);
      v += __shfl_xor(v, 16);
      acc[ai][px] = v;
    }
  if (cl == 0) {
#pragma unroll
    for (int ai = 0; ai < 4; ++ai) {
      float4 o = {acc[ai][0] + bias2, acc[ai][1] + bias2,
                  acc[ai][2] + bias2, acc[ai][3] + bias2};
      *(float4*)(out + (size_t)b * R * R + (oy0 + r0 + ai) * R + ox0 + 4 * g) = o;
    }
  }
}

// ---------------------------------------------------------------------------
extern "C" void kernel_launch(void* const* d_in, const int* in_sizes, int n_in,
                              void* d_out, int out_size, void* d_ws, size_t ws_size,
                              hipStream_t stream) {
  const float* yt = (const float*)d_in[0];  // (32,32,64,64)
  const float* Ht = (const float*)d_in[1];  // (32,256,256)
  const float* W1 = (const float*)d_in[2];  // (32,1,3,3)
  const float* b1 = (const float*)d_in[3];  // (32,)
  const float* W2 = (const float*)d_in[4];  // (1,32,3,3)
  const float* b2 = (const float*)d_in[5];  // (1,)
  float* outp = (float*)d_out;              // (32,1,256,256)
  float* x    = (float*)d_ws;               // 8 MB scratch

  einsum_kernel<<<512, 256, 0, stream>>>(yt, Ht, x);
  conv_fused_kernel<<<8192, 64, 0, stream>>>(x, W1, b1, W2, b2, outp);
}

// Round 11
// 142.995 us; speedup vs baseline: 1.3913x; 1.0200x over previous
//
#include <hip/hip_runtime.h>

#define R 256
#define T 32

#define TROWS 8         // out rows per wave tile
#define TCOLS 32        // out cols per wave tile
#define HR 10           // hidden rows stored (out rows + halo 1)
#define HC 34           // hidden cols stored (out cols + halo 1)
#define HSTR 36         // hidden row stride (words); hs col = hidden col + 1
#define CP 360          // plane stride words; %32=8 -> cl bank offsets {0,8,16,24}
#define WSLICE (4 * CP) // per-wave hs slice (1440 words = 5760 B)
#define NPX (HR * HC)   // 340 hidden px per wave tile
#define NSLOT 6

// In-wave LDS fence: DS pipe is in-order per wave; lgkmcnt(0) drains writes
// before subsequent reads issue. "memory" stops compiler reordering.
#define WAVE_FENCE() asm volatile("s_waitcnt lgkmcnt(0)" ::: "memory")

// ---------------------------------------------------------------------------
// Kernel A (unchanged R8 — dedup'd staging, known-good)
// ---------------------------------------------------------------------------
__global__ __launch_bounds__(256) void einsum_kernel(
    const float* __restrict__ yt, const float* __restrict__ Ht,
    float* __restrict__ x) {
  const int idx = blockIdx.x;
  const int rh  = idx >> 8;
  const int yy  = (idx & 255) >> 2;
  const int bq  = idx & 3;
  const int b0  = bq * 8;
  const int tid = threadIdx.x;
  const int q   = tid;
  const int q4  = q >> 2;

  __shared__ float yts[8 * 32 * 64];

#pragma unroll
  for (int i = 0; i < 16; ++i) {
    int f4  = tid + i * 256;
    int b_l = f4 >> 9;
    int t   = (f4 >> 4) & 31;
    int xx4 = f4 & 15;
    float4 v = *(const float4*)(yt + (((size_t)(b0 + b_l) * T + t) * 64 + yy) * 64 + xx4 * 4);
    *(float4*)(yts + f4 * 4) = v;
  }
  __syncthreads();

  for (int rr = 0; rr < 2; ++rr) {
    const int p = yy * 4 + rh * 2 + rr;
    float ht[T];
#pragma unroll
    for (int t = 0; t < T; ++t) ht[t] = Ht[((size_t)t * R + p) * R + q];

#pragma unroll
    for (int b_l = 0; b_l < 8; ++b_l) {
      const float* ys = yts + b_l * 2048 + q4;
      float acc = 0.f;
#pragma unroll
      for (int t = 0; t < T; ++t) acc += ht[t] * ys[t * 64];
      x[((size_t)(b0 + b_l) * R + p) * R + q] = acc;
    }
  }
}

// ---------------------------------------------------------------------------
// Kernel B: fused Conv(1->32,3x3) -> ReLU -> Conv(32->1,3x3), SAME.
// 256-thread blocks, FOUR independent wave-private 32x8 tiles, ZERO
// __syncthreads: each wave produces and consumes its own hs slice; ordering
// via in-wave lgkmcnt fences. Patches loaded straight from global (L1-hot),
// no xs staging. LDS 23 KB/block -> ~6 blocks/CU.
// ---------------------------------------------------------------------------
template <bool EDGE>
__device__ __forceinline__ void conv_body(
    const float (&patch)[NSLOT][9], bool slot5, const bool (&oob)[NSLOT],
    const int (&sw)[NSLOT], float* hs,
    const float* __restrict__ W1, const float* __restrict__ b1,
    const float* __restrict__ W2, int cl, int hboff, float (&acc)[4][4]) {
  for (int cg = 0; cg < 8; ++cg) {
    float w2[9];
#pragma unroll
    for (int k = 0; k < 9; ++k) w2[k] = W2[(cg * 4 + cl) * 9 + k];

    // ---- conv1 + relu: channels cg*4..cg*4+3 into this wave's 4 planes ----
#pragma unroll
    for (int c = 0; c < 4; ++c) {
      const int ch = cg * 4 + c;            // wave-uniform -> SGPR weights
      const float bias = b1[ch];
#pragma unroll
      for (int it = 0; it < NSLOT; ++it) {
        if (it < 5 || slot5) {
          float h = bias;
#pragma unroll
          for (int k = 0; k < 9; ++k) h += W1[ch * 9 + k] * patch[it][k];
          h = fmaxf(h, 0.f);
          if (EDGE) {
            if (oob[it]) h = 0.f;           // conv2 SAME: outside image = 0
          }
          hs[c * CP + sw[it]] = h;
        }
      }
    }
    WAVE_FENCE();   // writes drained before same wave reads them back

    // ---- conv2 partials: 6 rolling rows, each read once ----
#pragma unroll
    for (int j = 0; j < 6; ++j) {
      float4 v4 = *(const float4*)(hs + hboff + j * HSTR);
      float2 v2 = *(const float2*)(hs + hboff + j * HSTR + 4);
      float v[6] = {v4.x, v4.y, v4.z, v4.w, v2.x, v2.y};
#pragma unroll
      for (int dy = 0; dy < 3; ++dy) {
        int ai = j - dy;
        if (ai >= 0 && ai < 4) {
#pragma unroll
          for (int dx = 0; dx < 3; ++dx) {
            const float w = w2[dy * 3 + dx];
#pragma unroll
            for (int px = 0; px < 4; ++px) acc[ai][px] += w * v[px + dx];
          }
        }
      }
    }
    WAVE_FENCE();   // reads done before next group's conv1 overwrites (WAR)
  }
}

template <bool EDGE>
__device__ __forceinline__ void conv_tile(
    const float* __restrict__ xb, int ty0, int ox0, int lane, float* hsw,
    const float* __restrict__ W1, const float* __restrict__ b1,
    const float* __restrict__ W2, const float* __restrict__ b2,
    float* __restrict__ outp) {
  // --- per-lane 3x3 patches for hidden slots (10x34 grid, 340 px) ---
  float patch[NSLOT][9];
  int  sw[NSLOT];
  bool oob[NSLOT];
  const bool slot5 = (lane < NPX - 5 * 64);   // 20 lanes
#pragma unroll
  for (int it = 0; it < NSLOT; ++it) {
    int px = lane + it * 64;
    bool act = (it < 5) || slot5;
    int hy = act ? (px / HC) : 0;
    int hx = act ? (px % HC) : 0;
    sw[it] = hy * HSTR + hx;
    int ghy = ty0 - 1 + hy, ghx = ox0 - 1 + hx;
    oob[it] = !((ghy >= 0) & (ghy < R) & (ghx >= 0) & (ghx < R));
    if (EDGE) {
#pragma unroll
      for (int ky = 0; ky < 3; ++ky)
#pragma unroll
        for (int kx = 0; kx < 3; ++kx) {
          int gy = ty0 - 2 + hy + ky, gx = ox0 - 2 + hx + kx;
          bool ok = (gy >= 0) & (gy < R) & (gx >= 0) & (gx < R);
          patch[it][ky * 3 + kx] = ok ? xb[gy * R + gx] : 0.f;
        }
    } else {
      const float* gp = xb + (ty0 - 2 + hy) * R + (ox0 - 2 + hx);
#pragma unroll
      for (int ky = 0; ky < 3; ++ky)
#pragma unroll
        for (int kx = 0; kx < 3; ++kx)
          patch[it][ky * 3 + kx] = gp[ky * R + kx];  // imm-offset loads, L1-hot
    }
  }

  const int g  = lane & 7;          // col granule: px 4g..4g+3
  const int cl = (lane >> 3) & 3;   // channel in group
  const int rh = lane >> 5;         // 0..1: out rows 4rh..4rh+3
  const int r0 = 4 * rh;

  float acc[4][4];
#pragma unroll
  for (int ai = 0; ai < 4; ++ai)
#pragma unroll
    for (int px = 0; px < 4; ++px) acc[ai][px] = 0.f;

  const int hboff = cl * CP + r0 * HSTR + 4 * g;

  conv_body<EDGE>(patch, slot5, oob, sw, hsw, W1, b1, W2, cl, hboff, acc);

  // ---- reduce over the 4 channels (lane xor 8,16) and store ----
  const float bias2 = b2[0];
#pragma unroll
  for (int ai = 0; ai < 4; ++ai)
#pragma unroll
    for (int px = 0; px < 4; ++px) {
      float v = acc[ai][px];
      v += __shfl_xor(v, 8);
      v += __shfl_xor(v, 16);
      acc[ai][px] = v;
    }
  if (cl == 0) {
#pragma unroll
    for (int ai = 0; ai < 4; ++ai) {
      float4 o = {acc[ai][0] + bias2, acc[ai][1] + bias2,
                  acc[ai][2] + bias2, acc[ai][3] + bias2};
      *(float4*)(outp + (ty0 + r0 + ai) * R + ox0 + 4 * g) = o;
    }
  }
}

__global__ __launch_bounds__(256) void conv_fused_kernel(
    const float* __restrict__ x, const float* __restrict__ W1,
    const float* __restrict__ b1, const float* __restrict__ W2,
    const float* __restrict__ b2, float* __restrict__ out) {
  __shared__ float hs[4 * WSLICE];   // 23040 B, four private slices

  const int tid  = threadIdx.x;
  const int lane = tid & 63;
  const int wv   = tid >> 6;
  const int b    = blockIdx.x >> 6;
  const int tile = blockIdx.x & 63;          // 8x8 grid of 32x32 block tiles
  const int ty0  = (tile >> 3) * 32 + wv * TROWS;  // this wave's row base
  const int ox0  = (tile & 7) * TCOLS;
  const float* xb   = x + (size_t)b * R * R;
  float*       outp = out + (size_t)b * R * R;
  float*       hsw  = hs + wv * WSLICE;

  const bool edge = (ty0 == 0) | (ty0 == R - TROWS) | (ox0 == 0) | (ox0 == R - TCOLS);
  if (edge)
    conv_tile<true>(xb, ty0, ox0, lane, hsw, W1, b1, W2, b2, outp);
  else
    conv_tile<false>(xb, ty0, ox0, lane, hsw, W1, b1, W2, b2, outp);
}

// ---------------------------------------------------------------------------
extern "C" void kernel_launch(void* const* d_in, const int* in_sizes, int n_in,
                              void* d_out, int out_size, void* d_ws, size_t ws_size,
                              hipStream_t stream) {
  const float* yt = (const float*)d_in[0];  // (32,32,64,64)
  const float* Ht = (const float*)d_in[1];  // (32,256,256)
  const float* W1 = (const float*)d_in[2];  // (32,1,3,3)
  const float* b1 = (const float*)d_in[3];  // (32,)
  const float* W2 = (const float*)d_in[4];  // (1,32,3,3)
  const float* b2 = (const float*)d_in[5];  // (1,)
  float* outp = (float*)d_out;              // (32,1,256,256)
  float* x    = (float*)d_ws;               // 8 MB scratch

  einsum_kernel<<<512, 256, 0, stream>>>(yt, Ht, x);
  conv_fused_kernel<<<2048, 256, 0, stream>>>(x, W1, b1, W2, b2, outp);
}

// Round 12
// 132.529 us; speedup vs baseline: 1.5012x; 1.0790x over previous
//
#include <hip/hip_runtime.h>

#define R 256
#define T 32

#define TROWS 8         // out rows per wave tile
#define TCOLS 32        // out cols per wave tile
#define HR 10           // hidden rows stored (out rows + halo 1)
#define HC 34           // hidden cols stored (out cols + halo 1)
#define HSTR 36         // hidden row stride (words); hs col = hidden col + 1
#define CP 360          // plane stride words; %32=8 -> cl bank offsets {0,8,16,24}
#define WSLICE (4 * CP) // per-wave hs slice (5760 B)
#define NPX (HR * HC)   // 340 hidden px per wave tile

typedef float v2f __attribute__((ext_vector_type(2)));
#define FMA2(a, b, c) __builtin_elementwise_fma((a), (b), (c))

// ---------------------------------------------------------------------------
// Kernel A (unchanged R8 — dedup'd staging, known-good)
// ---------------------------------------------------------------------------
__global__ __launch_bounds__(256) void einsum_kernel(
    const float* __restrict__ yt, const float* __restrict__ Ht,
    float* __restrict__ x) {
  const int idx = blockIdx.x;
  const int rh  = idx >> 8;
  const int yy  = (idx & 255) >> 2;
  const int bq  = idx & 3;
  const int b0  = bq * 8;
  const int tid = threadIdx.x;
  const int q   = tid;
  const int q4  = q >> 2;

  __shared__ float yts[8 * 32 * 64];

#pragma unroll
  for (int i = 0; i < 16; ++i) {
    int f4  = tid + i * 256;
    int b_l = f4 >> 9;
    int t   = (f4 >> 4) & 31;
    int xx4 = f4 & 15;
    float4 v = *(const float4*)(yt + (((size_t)(b0 + b_l) * T + t) * 64 + yy) * 64 + xx4 * 4);
    *(float4*)(yts + f4 * 4) = v;
  }
  __syncthreads();

  for (int rr = 0; rr < 2; ++rr) {
    const int p = yy * 4 + rh * 2 + rr;
    float ht[T];
#pragma unroll
    for (int t = 0; t < T; ++t) ht[t] = Ht[((size_t)t * R + p) * R + q];

#pragma unroll
    for (int b_l = 0; b_l < 8; ++b_l) {
      const float* ys = yts + b_l * 2048 + q4;
      float acc = 0.f;
#pragma unroll
      for (int t = 0; t < T; ++t) acc += ht[t] * ys[t * 64];
      x[((size_t)(b0 + b_l) * R + p) * R + q] = acc;
    }
  }
}

// ---------------------------------------------------------------------------
// Kernel B: fused Conv(1->32,3x3) -> ReLU -> Conv(32->1,3x3), SAME.
// R11 skeleton (wave-private 32x8 tiles, no barriers) + PACKED fp32 math:
// conv1 pairs hidden-px slots, conv2 pairs output pixels -> v_pk_fma_f32
// halves FMA issue. No explicit fences: DS ops complete in-order per wave;
// compiler's may-alias analysis on hs preserves program order.
// ---------------------------------------------------------------------------
template <bool EDGE>
__device__ __forceinline__ void conv_body(
    const v2f (&patch2)[3][9], bool slot5, const bool (&oob)[6],
    const int (&sw)[6], float* hs,
    const float* __restrict__ W1, const float* __restrict__ b1,
    const float* __restrict__ W2, int cl, int hboff, v2f (&acc2)[4][2]) {
  for (int cg = 0; cg < 8; ++cg) {
    float w2[9];
#pragma unroll
    for (int k = 0; k < 9; ++k) w2[k] = W2[(cg * 4 + cl) * 9 + k];

    // ---- conv1 + relu: channels cg*4..cg*4+3 into this wave's 4 planes ----
#pragma unroll
    for (int c = 0; c < 4; ++c) {
      const int ch = cg * 4 + c;            // wave-uniform -> SGPR weights
      const float bias = b1[ch];
      v2f h0 = {bias, bias}, h1 = {bias, bias}, h2 = {bias, bias};
#pragma unroll
      for (int k = 0; k < 9; ++k) {
        const float w = W1[ch * 9 + k];
        const v2f wv = {w, w};
        h0 = FMA2(wv, patch2[0][k], h0);
        h1 = FMA2(wv, patch2[1][k], h1);
        h2 = FMA2(wv, patch2[2][k], h2);
      }
      const v2f z = {0.f, 0.f};
      h0 = __builtin_elementwise_max(h0, z);
      h1 = __builtin_elementwise_max(h1, z);
      h2 = __builtin_elementwise_max(h2, z);
      if (EDGE) {
        if (oob[0]) h0.x = 0.f;
        if (oob[1]) h0.y = 0.f;
        if (oob[2]) h1.x = 0.f;
        if (oob[3]) h1.y = 0.f;
        if (oob[4]) h2.x = 0.f;
        if (oob[5]) h2.y = 0.f;
      }
      float* hp = hs + c * CP;
      hp[sw[0]] = h0.x;
      hp[sw[1]] = h0.y;
      hp[sw[2]] = h1.x;
      hp[sw[3]] = h1.y;
      hp[sw[4]] = h2.x;
      if (slot5) hp[sw[5]] = h2.y;
    }

    // ---- conv2 partials: 6 rolling rows, packed px pairs ----
#pragma unroll
    for (int j = 0; j < 6; ++j) {
      float4 v4 = *(const float4*)(hs + hboff + j * HSTR);
      float2 vt = *(const float2*)(hs + hboff + j * HSTR + 4);
      v2f P[5];
      P[0] = (v2f){v4.x, v4.y};
      P[1] = (v2f){v4.y, v4.z};
      P[2] = (v2f){v4.z, v4.w};
      P[3] = (v2f){v4.w, vt.x};
      P[4] = (v2f){vt.x, vt.y};
#pragma unroll
      for (int dy = 0; dy < 3; ++dy) {
        int ai = j - dy;
        if (ai >= 0 && ai < 4) {
#pragma unroll
          for (int dx = 0; dx < 3; ++dx) {
            const float w = w2[dy * 3 + dx];
            const v2f wv = {w, w};
            acc2[ai][0] = FMA2(wv, P[dx], acc2[ai][0]);
            acc2[ai][1] = FMA2(wv, P[dx + 2], acc2[ai][1]);
          }
        }
      }
    }
  }
}

template <bool EDGE>
__device__ __forceinline__ void conv_tile(
    const float* __restrict__ xb, int ty0, int ox0, int lane, float* hsw,
    const float* __restrict__ W1, const float* __restrict__ b1,
    const float* __restrict__ W2, const float* __restrict__ b2,
    float* __restrict__ outp) {
  // --- per-lane 3x3 patches, slot-paired: pair p = slots (2p, 2p+1) ---
  v2f  patch2[3][9];
  int  sw[6];
  bool oob[6];
  const bool slot5 = (lane < NPX - 5 * 64);   // 20 lanes
#pragma unroll
  for (int it = 0; it < 6; ++it) {
    int px = lane + it * 64;
    bool act = (it < 5) || slot5;
    int hy = act ? (px / HC) : 0;
    int hx = act ? (px % HC) : 0;
    sw[it] = hy * HSTR + hx;
    int ghy = ty0 - 1 + hy, ghx = ox0 - 1 + hx;
    oob[it] = !((ghy >= 0) & (ghy < R) & (ghx >= 0) & (ghx < R));
#pragma unroll
    for (int ky = 0; ky < 3; ++ky)
#pragma unroll
      for (int kx = 0; kx < 3; ++kx) {
        float pv;
        if (EDGE) {
          int gy = ty0 - 2 + hy + ky, gx = ox0 - 2 + hx + kx;
          bool ok = (gy >= 0) & (gy < R) & (gx >= 0) & (gx < R);
          pv = ok ? xb[gy * R + gx] : 0.f;
        } else {
          pv = xb[(ty0 - 2 + hy + ky) * R + (ox0 - 2 + hx + kx)];
        }
        if (it & 1) patch2[it >> 1][ky * 3 + kx].y = pv;
        else        patch2[it >> 1][ky * 3 + kx].x = pv;
      }
  }

  const int g  = lane & 7;          // col granule: px 4g..4g+3
  const int cl = (lane >> 3) & 3;   // channel in group
  const int rh = lane >> 5;         // 0..1: out rows 4rh..4rh+3
  const int r0 = 4 * rh;

  v2f acc2[4][2];
#pragma unroll
  for (int ai = 0; ai < 4; ++ai) {
    acc2[ai][0] = (v2f){0.f, 0.f};
    acc2[ai][1] = (v2f){0.f, 0.f};
  }

  const int hboff = cl * CP + r0 * HSTR + 4 * g;

  conv_body<EDGE>(patch2, slot5, oob, sw, hsw, W1, b1, W2, cl, hboff, acc2);

  // ---- reduce over the 4 channels (lane xor 8,16) and store ----
  const float bias2 = b2[0];
#pragma unroll
  for (int ai = 0; ai < 4; ++ai)
#pragma unroll
    for (int h = 0; h < 2; ++h) {
      float vx = acc2[ai][h].x, vy = acc2[ai][h].y;
      vx += __shfl_xor(vx, 8);  vy += __shfl_xor(vy, 8);
      vx += __shfl_xor(vx, 16); vy += __shfl_xor(vy, 16);
      acc2[ai][h].x = vx; acc2[ai][h].y = vy;
    }
  if (cl == 0) {
#pragma unroll
    for (int ai = 0; ai < 4; ++ai) {
      float4 o = {acc2[ai][0].x + bias2, acc2[ai][0].y + bias2,
                  acc2[ai][1].x + bias2, acc2[ai][1].y + bias2};
      *(float4*)(outp + (ty0 + r0 + ai) * R + ox0 + 4 * g) = o;
    }
  }
}

__global__ __launch_bounds__(256) void conv_fused_kernel(
    const float* __restrict__ x, const float* __restrict__ W1,
    const float* __restrict__ b1, const float* __restrict__ W2,
    const float* __restrict__ b2, float* __restrict__ out) {
  __shared__ float hs[4 * WSLICE];   // 23040 B, four private slices

  const int tid  = threadIdx.x;
  const int lane = tid & 63;
  const int wv   = tid >> 6;
  const int b    = blockIdx.x >> 6;
  const int tile = blockIdx.x & 63;          // 8x8 grid of 32x32 block tiles
  const int ty0  = (tile >> 3) * 32 + wv * TROWS;
  const int ox0  = (tile & 7) * TCOLS;
  const float* xb   = x + (size_t)b * R * R;
  float*       outp = out + (size_t)b * R * R;
  float*       hsw  = hs + wv * WSLICE;

  const bool edge = (ty0 == 0) | (ty0 == R - TROWS) | (ox0 == 0) | (ox0 == R - TCOLS);
  if (edge)
    conv_tile<true>(xb, ty0, ox0, lane, hsw, W1, b1, W2, b2, outp);
  else
    conv_tile<false>(xb, ty0, ox0, lane, hsw, W1, b1, W2, b2, outp);
}

// ---------------------------------------------------------------------------
extern "C" void kernel_launch(void* const* d_in, const int* in_sizes, int n_in,
                              void* d_out, int out_size, void* d_ws, size_t ws_size,
                              hipStream_t stream) {
  const float* yt = (const float*)d_in[0];  // (32,32,64,64)
  const float* Ht = (const float*)d_in[1];  // (32,256,256)
  const float* W1 = (const float*)d_in[2];  // (32,1,3,3)
  const float* b1 = (const float*)d_in[3];  // (32,)
  const float* W2 = (const float*)d_in[4];  // (1,32,3,3)
  const float* b2 = (const float*)d_in[5];  // (1,)
  float* outp = (float*)d_out;              // (32,1,256,256)
  float* x    = (float*)d_ws;               // 8 MB scratch

  einsum_kernel<<<512, 256, 0, stream>>>(yt, Ht, x);
  conv_fused_kernel<<<2048, 256, 0, stream>>>(x, W1, b1, W2, b2, outp);
}

// Round 13
// 130.592 us; speedup vs baseline: 1.5234x; 1.0148x over previous
//
#include <hip/hip_runtime.h>

#define R 256
#define T 32

#define TROWS 8         // out rows per wave tile
#define TCOLS 32        // out cols per wave tile
#define HR 10           // hidden rows stored (out rows + halo 1)
#define HC 34           // hidden cols stored (out cols + halo 1) — EVEN: px pairs never straddle rows
#define HSTR 36         // hidden row stride (words)
#define CP 360          // plane stride words; %32=8 -> cl bank offsets {0,8,16,24}
#define WSLICE (4 * CP) // per-wave hs slice (5760 B)
#define NPX (HR * HC)   // 340 hidden px per wave tile
#define NPAIR (NPX / 2) // 170 px pairs; slots 0,1 full, slot 2 active for lane<42

typedef float v2f __attribute__((ext_vector_type(2)));
#define FMA2(a, b, c) __builtin_elementwise_fma((a), (b), (c))

// ---------------------------------------------------------------------------
// Kernel A (unchanged R8 — dedup'd staging, known-good)
// ---------------------------------------------------------------------------
__global__ __launch_bounds__(256) void einsum_kernel(
    const float* __restrict__ yt, const float* __restrict__ Ht,
    float* __restrict__ x) {
  const int idx = blockIdx.x;
  const int rh  = idx >> 8;
  const int yy  = (idx & 255) >> 2;
  const int bq  = idx & 3;
  const int b0  = bq * 8;
  const int tid = threadIdx.x;
  const int q   = tid;
  const int q4  = q >> 2;

  __shared__ float yts[8 * 32 * 64];

#pragma unroll
  for (int i = 0; i < 16; ++i) {
    int f4  = tid + i * 256;
    int b_l = f4 >> 9;
    int t   = (f4 >> 4) & 31;
    int xx4 = f4 & 15;
    float4 v = *(const float4*)(yt + (((size_t)(b0 + b_l) * T + t) * 64 + yy) * 64 + xx4 * 4);
    *(float4*)(yts + f4 * 4) = v;
  }
  __syncthreads();

  for (int rr = 0; rr < 2; ++rr) {
    const int p = yy * 4 + rh * 2 + rr;
    float ht[T];
#pragma unroll
    for (int t = 0; t < T; ++t) ht[t] = Ht[((size_t)t * R + p) * R + q];

#pragma unroll
    for (int b_l = 0; b_l < 8; ++b_l) {
      const float* ys = yts + b_l * 2048 + q4;
      float acc = 0.f;
#pragma unroll
      for (int t = 0; t < T; ++t) acc += ht[t] * ys[t * 64];
      x[((size_t)(b0 + b_l) * R + p) * R + q] = acc;
    }
  }
}

// ---------------------------------------------------------------------------
// Kernel B: fused Conv(1->32,3x3) -> ReLU -> Conv(32->1,3x3), SAME.
// R12 skeleton + CONTIGUOUS px pairs per lane: pair pi = lane + it*64 owns
// hidden px (2pi, 2pi+1) — same row (HC even). Stores are ds_write_b64,
// patch windows overlap -> dwordx2 loads. pk math identical to R12.
// ---------------------------------------------------------------------------
template <bool EDGE>
__device__ __forceinline__ void conv_body(
    const v2f (&patch2)[3][9], bool slot2, const bool (&oob)[6],
    const int (&sw)[3], float* hs,
    const float* __restrict__ W1, const float* __restrict__ b1,
    const float* __restrict__ W2, int cl, int hboff, v2f (&acc2)[4][2]) {
  for (int cg = 0; cg < 8; ++cg) {
    float w2[9];
#pragma unroll
    for (int k = 0; k < 9; ++k) w2[k] = W2[(cg * 4 + cl) * 9 + k];

    // ---- conv1 + relu: channels cg*4..cg*4+3 into this wave's 4 planes ----
#pragma unroll
    for (int c = 0; c < 4; ++c) {
      const int ch = cg * 4 + c;            // wave-uniform -> SGPR weights
      const float bias = b1[ch];
      v2f h0 = {bias, bias}, h1 = {bias, bias}, h2 = {bias, bias};
#pragma unroll
      for (int k = 0; k < 9; ++k) {
        const float w = W1[ch * 9 + k];
        const v2f wv = {w, w};
        h0 = FMA2(wv, patch2[0][k], h0);
        h1 = FMA2(wv, patch2[1][k], h1);
        h2 = FMA2(wv, patch2[2][k], h2);
      }
      const v2f z = {0.f, 0.f};
      h0 = __builtin_elementwise_max(h0, z);
      h1 = __builtin_elementwise_max(h1, z);
      h2 = __builtin_elementwise_max(h2, z);
      if (EDGE) {
        if (oob[0]) h0.x = 0.f;
        if (oob[1]) h0.y = 0.f;
        if (oob[2]) h1.x = 0.f;
        if (oob[3]) h1.y = 0.f;
        if (oob[4]) h2.x = 0.f;
        if (oob[5]) h2.y = 0.f;
      }
      float* hp = hs + c * CP;
      *(v2f*)(hp + sw[0]) = h0;            // ds_write_b64 (8B-aligned)
      *(v2f*)(hp + sw[1]) = h1;
      if (slot2) *(v2f*)(hp + sw[2]) = h2;
    }

    // ---- conv2 partials: 6 rolling rows, packed px pairs (unchanged) ----
#pragma unroll
    for (int j = 0; j < 6; ++j) {
      float4 v4 = *(const float4*)(hs + hboff + j * HSTR);
      float2 vt = *(const float2*)(hs + hboff + j * HSTR + 4);
      v2f P[5];
      P[0] = (v2f){v4.x, v4.y};
      P[1] = (v2f){v4.y, v4.z};
      P[2] = (v2f){v4.z, v4.w};
      P[3] = (v2f){v4.w, vt.x};
      P[4] = (v2f){vt.x, vt.y};
#pragma unroll
      for (int dy = 0; dy < 3; ++dy) {
        int ai = j - dy;
        if (ai >= 0 && ai < 4) {
#pragma unroll
          for (int dx = 0; dx < 3; ++dx) {
            const float w = w2[dy * 3 + dx];
            const v2f wv = {w, w};
            acc2[ai][0] = FMA2(wv, P[dx], acc2[ai][0]);
            acc2[ai][1] = FMA2(wv, P[dx + 2], acc2[ai][1]);
          }
        }
      }
    }
  }
}

template <bool EDGE>
__device__ __forceinline__ void conv_tile(
    const float* __restrict__ xb, int ty0, int ox0, int lane, float* hsw,
    const float* __restrict__ W1, const float* __restrict__ b1,
    const float* __restrict__ W2, const float* __restrict__ b2,
    float* __restrict__ outp) {
  // --- per-lane patches for 3 CONTIGUOUS px pairs: pi = lane + it*64 ---
  v2f  patch2[3][9];
  int  sw[3];
  bool oob[6];
  const bool slot2 = (lane < NPAIR - 2 * 64);   // 42 lanes
#pragma unroll
  for (int it = 0; it < 3; ++it) {
    int pi = lane + it * 64;
    bool act = (it < 2) || slot2;
    int px0 = 2 * pi;
    int hy  = act ? (px0 / HC) : 0;
    int hx0 = act ? (px0 % HC) : 0;       // even
    sw[it] = hy * HSTR + hx0;             // even -> b64-aligned
    int ghy = ty0 - 1 + hy;
    int ghx0 = ox0 - 1 + hx0;
    bool rowok = (ghy >= 0) & (ghy < R);
    oob[2 * it]     = !(rowok & (ghx0 >= 0) & (ghx0 < R));
    oob[2 * it + 1] = !(rowok & (ghx0 + 1 >= 0) & (ghx0 + 1 < R));
#pragma unroll
    for (int ky = 0; ky < 3; ++ky) {
      const int gy  = ty0 - 2 + hy + ky;
      const int gx0 = ox0 - 2 + hx0;      // even -> 8B-aligned
      v2f fa, fb;
      if (EDGE) {
        float xv[4];
#pragma unroll
        for (int c = 0; c < 4; ++c) {
          int gx = gx0 + c;
          bool ok = act & (gy >= 0) & (gy < R) & (gx >= 0) & (gx < R);
          xv[c] = ok ? xb[gy * R + gx] : 0.f;
        }
        fa = (v2f){xv[0], xv[1]};
        fb = (v2f){xv[2], xv[3]};
      } else {
        const float* xp = xb + gy * R + gx0;
        fa = act ? *(const v2f*)(xp)     : (v2f){0.f, 0.f};
        fb = act ? *(const v2f*)(xp + 2) : (v2f){0.f, 0.f};
      }
      patch2[it][3 * ky + 0] = fa;
      patch2[it][3 * ky + 1] = (v2f){fa.y, fb.x};
      patch2[it][3 * ky + 2] = fb;
    }
  }

  const int g  = lane & 7;          // col granule: px 4g..4g+3
  const int cl = (lane >> 3) & 3;   // channel in group
  const int rh = lane >> 5;         // 0..1: out rows 4rh..4rh+3
  const int r0 = 4 * rh;

  v2f acc2[4][2];
#pragma unroll
  for (int ai = 0; ai < 4; ++ai) {
    acc2[ai][0] = (v2f){0.f, 0.f};
    acc2[ai][1] = (v2f){0.f, 0.f};
  }

  const int hboff = cl * CP + r0 * HSTR + 4 * g;

  conv_body<EDGE>(patch2, slot2, oob, sw, hsw, W1, b1, W2, cl, hboff, acc2);

  // ---- reduce over the 4 channels (lane xor 8,16) and store ----
  const float bias2 = b2[0];
#pragma unroll
  for (int ai = 0; ai < 4; ++ai)
#pragma unroll
    for (int h = 0; h < 2; ++h) {
      float vx = acc2[ai][h].x, vy = acc2[ai][h].y;
      vx += __shfl_xor(vx, 8);  vy += __shfl_xor(vy, 8);
      vx += __shfl_xor(vx, 16); vy += __shfl_xor(vy, 16);
      acc2[ai][h].x = vx; acc2[ai][h].y = vy;
    }
  if (cl == 0) {
#pragma unroll
    for (int ai = 0; ai < 4; ++ai) {
      float4 o = {acc2[ai][0].x + bias2, acc2[ai][0].y + bias2,
                  acc2[ai][1].x + bias2, acc2[ai][1].y + bias2};
      *(float4*)(outp + (ty0 + r0 + ai) * R + ox0 + 4 * g) = o;
    }
  }
}

__global__ __launch_bounds__(256) void conv_fused_kernel(
    const float* __restrict__ x, const float* __restrict__ W1,
    const float* __restrict__ b1, const float* __restrict__ W2,
    const float* __restrict__ b2, float* __restrict__ out) {
  __shared__ float hs[4 * WSLICE];   // 23040 B, four private slices

  const int tid  = threadIdx.x;
  const int lane = tid & 63;
  const int wv   = tid >> 6;
  const int b    = blockIdx.x >> 6;
  const int tile = blockIdx.x & 63;          // 8x8 grid of 32x32 block tiles
  const int ty0  = (tile >> 3) * 32 + wv * TROWS;
  const int ox0  = (tile & 7) * TCOLS;
  const float* xb   = x + (size_t)b * R * R;
  float*       outp = out + (size_t)b * R * R;
  float*       hsw  = hs + wv * WSLICE;

  const bool edge = (ty0 == 0) | (ty0 == R - TROWS) | (ox0 == 0) | (ox0 == R - TCOLS);
  if (edge)
    conv_tile<true>(xb, ty0, ox0, lane, hsw, W1, b1, W2, b2, outp);
  else
    conv_tile<false>(xb, ty0, ox0, lane, hsw, W1, b1, W2, b2, outp);
}

// ---------------------------------------------------------------------------
extern "C" void kernel_launch(void* const* d_in, const int* in_sizes, int n_in,
                              void* d_out, int out_size, void* d_ws, size_t ws_size,
                              hipStream_t stream) {
  const float* yt = (const float*)d_in[0];  // (32,32,64,64)
  const float* Ht = (const float*)d_in[1];  // (32,256,256)
  const float* W1 = (const float*)d_in[2];  // (32,1,3,3)
  const float* b1 = (const float*)d_in[3];  // (32,)
  const float* W2 = (const float*)d_in[4];  // (1,32,3,3)
  const float* b2 = (const float*)d_in[5];  // (1,)
  float* outp = (float*)d_out;              // (32,1,256,256)
  float* x    = (float*)d_ws;               // 8 MB scratch

  einsum_kernel<<<512, 256, 0, stream>>>(yt, Ht, x);
  conv_fused_kernel<<<2048, 256, 0, stream>>>(x, W1, b1, W2, b2, outp);
}